// Round 16
// baseline (91.747 us; speedup 1.0000x reference)
//
#include <hip/hip_runtime.h>
#include <hip/hip_bf16.h>
#include <stdint.h>

typedef unsigned short u16;
typedef short short8 __attribute__((ext_vector_type(8)));
typedef float f32x4 __attribute__((ext_vector_type(4)));

#define SEQ 2048
#define EMB 1024
#define NH 16
#define HD 64
#define ZP 2112  // SEQ + 64 pad, reversed z per (b,h)

__device__ inline u16 f2bf(float f) {
    uint32_t u = __builtin_bit_cast(uint32_t, f);
    uint32_t r = (u + 0x7FFFu + ((u >> 16) & 1u)) >> 16;
    return (u16)r;
}

__device__ inline void gload16(const void* g, void* l) {
    __builtin_amdgcn_global_load_lds(
        (const __attribute__((address_space(1))) void*)g,
        (__attribute__((address_space(3))) void*)l, 16, 0, 0);
}

// ---------------- weights cast only: W_V, W_O fp32 -> bf16 (x never cast) ----------------
__global__ __launch_bounds__(256) void cast_w(const float* __restrict__ W_V,
                                              const float* __restrict__ W_O,
                                              u16* __restrict__ wvb,
                                              u16* __restrict__ wob) {
    int j = blockIdx.x * 256 + threadIdx.x;
    const float* src;
    u16* dst;
    if (j < 262144) { src = W_V; dst = wvb; }
    else { j -= 262144; src = W_O; dst = wob; }
    float4 f = reinterpret_cast<const float4*>(src)[j];
    union { u16 u[4]; uint2 v; } o;
    o.u[0] = f2bf(f.x); o.u[1] = f2bf(f.y); o.u[2] = f2bf(f.z); o.u[3] = f2bf(f.w);
    reinterpret_cast<uint2*>(dst)[j] = o.v;
}

// ---------------- logits: zl[b][h][s] = dot(x[b,s,:], W_A[h,:]) * 0.125 ----------------
__global__ __launch_bounds__(256) void logits_kernel(const float* __restrict__ x,
                                                     const float* __restrict__ W_A,
                                                     float* __restrict__ zl) {
    __shared__ float wa[NH * EMB]; // 64 KB
    int t = threadIdx.x;
    for (int i = t; i < NH * EMB / 4; i += 256)
        reinterpret_cast<float4*>(wa)[i] = reinterpret_cast<const float4*>(W_A)[i];
    __syncthreads();
    int w = t >> 6, l = t & 63;
    int row0 = blockIdx.x * 16 + w * 4;
    for (int rr = 0; rr < 4; rr++) {
        int gs = row0 + rr;           // 0..4095 = b*SEQ + s
        int b = gs >> 11, s = gs & 2047;
        const float* xr = x + (size_t)gs * EMB;
        float xv[16];
#pragma unroll
        for (int q = 0; q < 16; q++) xv[q] = xr[l + 64 * q];
#pragma unroll
        for (int h = 0; h < NH; h++) {
            float a = 0.f;
#pragma unroll
            for (int q = 0; q < 16; q++) a += xv[q] * wa[h * EMB + l + 64 * q];
#pragma unroll
            for (int off = 32; off; off >>= 1) a += __shfl_xor(a, off);
            if (l == h) zl[((size_t)b * NH + h) * SEQ + s] = a * 0.125f;
        }
    }
}

// ---------------- softmax body (per bh), 512 threads ----------------
__device__ void softmax_body512(const float* __restrict__ zl, u16* __restrict__ zr, int bh) {
    const float* src = zl + (size_t)bh * SEQ;
    int t = threadIdx.x;
    int w = t >> 6, l = t & 63;
    __shared__ float red[8];
    __shared__ float bc;
    float v[4];
#pragma unroll
    for (int q = 0; q < 4; q++) v[q] = src[t + 512 * q];
    float m = fmaxf(fmaxf(v[0], v[1]), fmaxf(v[2], v[3]));
#pragma unroll
    for (int off = 32; off; off >>= 1) m = fmaxf(m, __shfl_xor(m, off));
    if (l == 0) red[w] = m;
    __syncthreads();
    if (t == 0) {
        float mm = red[0];
#pragma unroll
        for (int q = 1; q < 8; q++) mm = fmaxf(mm, red[q]);
        bc = mm;
    }
    __syncthreads();
    m = bc;
    float s = 0.f;
#pragma unroll
    for (int q = 0; q < 4; q++) { v[q] = expf(v[q] - m); s += v[q]; }
#pragma unroll
    for (int off = 32; off; off >>= 1) s += __shfl_xor(s, off);
    if (l == 0) red[w] = s;
    __syncthreads();
    if (t == 0) {
        float ss = 0.f;
#pragma unroll
        for (int q = 0; q < 8; q++) ss += red[q];
        bc = ss;
    }
    __syncthreads();
    float inv = 1.0f / bc;
#pragma unroll
    for (int q = 0; q < 4; q++) {
        int sidx = t + 512 * q;
        zr[(size_t)bh * ZP + (SEQ - 1 - sidx)] = f2bf(v[q] * inv);
    }
    if (t < ZP - SEQ) zr[(size_t)bh * ZP + SEQ + t] = 0;
}

// ---------------- GEMM: C[M,N] = A[M,K] * B[N,K]^T -- R12 geometry; optional fp32-B ----------
// 128x64 tile, 512 threads = 8 waves (4 row-groups x 2 col-groups), wave 32x32
// acc[2][2], BK=64 dbuf, plain __syncthreads 2-phase (89.5us-best config).
// F32B: B-operand read DIRECTLY from fp32 global (x, L3-hot from logits):
// per thread 2x float4 -> cvt bf16 -> ds_write_b128 into the SAME swizzled slot
// (plain ds_write has no wave-uniform constraint). T14 split: issue B-loads for
// kt+1 -> compute kt -> cvt+write -> barrier (global latency hides under MFMA).
// Deletes the xb intermediate (8MB write + 8MB read + cast-kernel 16MB read).
// Swizzle pair (rule #21): source/write chunk c^(row&7), read ck^(lrow&7) -> 2-way, free.
// OUTMODE 0: bf16 out; 1: fp32 out + bias. SM: tail softmax.
template <int OUTMODE, int MAP, bool SM, bool F32B>
__global__ __launch_bounds__(512, 4) void gemm32(const u16* __restrict__ A,
                                                 const u16* __restrict__ Bw,
                                                 const float* __restrict__ Bf,
                                                 u16* __restrict__ Cb, float* __restrict__ Cf,
                                                 const float* __restrict__ bias,
                                                 int M, int N, int K,
                                                 const float* __restrict__ zl,
                                                 u16* __restrict__ zr) {
    if constexpr (SM) {
        if (blockIdx.x >= 512) { softmax_body512(zl, zr, blockIdx.x - 512); return; }
    }
    __shared__ u16 As[2][128 * 64];   // 16 KB each
    __shared__ u16 Bs[2][64 * 64];    //  8 KB each -> 48 KB total
    const int t = threadIdx.x;
    const int i = blockIdx.x;
    int xg, yg;
    if constexpr (MAP == 0) { xg = (i & 7) * 8 + ((i >> 3) & 7); yg = i >> 6; }
    else                    { yg = (i & 7) * 4 + ((i >> 3) & 3); xg = i >> 5; }
    const int m0 = yg * 128, n0 = xg * 64;
    const int w = t >> 6, l = t & 63;
    const int wr = w & 3, wc = w >> 2;        // wave tile 32 rows x 32 cols
    const int lrow = l & 15, lk = l >> 4;
    const int r7 = lrow & 7;

    // A staging (gload16: XOR'd per-lane source, wave-uniform linear dest)
    const int csrc = ((l & 7) ^ (l >> 3)) * 8;     // u16 offset within BK row
    const u16* gA0 = A + (size_t)(m0 + w * 16 + (l >> 3)) * K + csrc;
    const u16* gA1 = gA0 + (size_t)8 * K;
    const int dA0 = w * 1024, dA1 = w * 1024 + 512;  // u16 units

    // B staging
    const u16* gB;
    const float* fB;
    int dB = 0, dBw = 0;
    if constexpr (F32B) {
        fB = Bf + (size_t)(n0 + (t >> 3)) * K + (t & 7) * 8;           // fp32 source
        dBw = (t >> 3) * 64 + (((t & 7) ^ ((t >> 3) & 7)) * 8);        // swizzled write slot
    } else {
        gB = Bw + (size_t)(n0 + w * 8 + (l >> 3)) * K + csrc;
        dB = w * 512;
    }

    f32x4 acc[2][2];
#pragma unroll
    for (int a = 0; a < 2; a++)
#pragma unroll
        for (int b = 0; b < 2; b++) acc[a][b] = (f32x4){0.f, 0.f, 0.f, 0.f};

    auto writeB = [&](int buf, float4 u0, float4 u1) {
        union { u16 u[8]; uint4 v; } o;
        o.u[0] = f2bf(u0.x); o.u[1] = f2bf(u0.y); o.u[2] = f2bf(u0.z); o.u[3] = f2bf(u0.w);
        o.u[4] = f2bf(u1.x); o.u[5] = f2bf(u1.y); o.u[6] = f2bf(u1.z); o.u[7] = f2bf(u1.w);
        *reinterpret_cast<uint4*>(&Bs[buf][dBw]) = o.v;
    };

    const int NT = K >> 6;
    // prologue: stage tile 0
    gload16(gA0, &As[0][dA0]);
    gload16(gA1, &As[0][dA1]);
    if constexpr (F32B) {
        float4 u0 = *reinterpret_cast<const float4*>(fB);
        float4 u1 = *reinterpret_cast<const float4*>(fB + 4);
        writeB(0, u0, u1);
    } else {
        gload16(gB, &Bs[0][dB]);
    }
    __syncthreads();

    for (int kt = 0; kt < NT; kt++) {
        const int cur = kt & 1;
        float4 u0, u1;
        if (kt + 1 < NT) {
            const int k0 = (kt + 1) * 64;
            if constexpr (F32B) {
                u0 = *reinterpret_cast<const float4*>(fB + k0);      // issue early;
                u1 = *reinterpret_cast<const float4*>(fB + k0 + 4);  // wait lands after compute
            } else {
                gload16(gB + k0, &Bs[cur ^ 1][dB]);
            }
            gload16(gA0 + k0, &As[cur ^ 1][dA0]);
            gload16(gA1 + k0, &As[cur ^ 1][dA1]);
        }
#pragma unroll
        for (int kk = 0; kk < 2; kk++) {
            const int cs = ((kk * 4 + lk) ^ r7) * 8;
            short8 af[2], bf2[2];
#pragma unroll
            for (int mi = 0; mi < 2; mi++)
                af[mi] = *reinterpret_cast<const short8*>(
                    &As[cur][(wr * 32 + mi * 16 + lrow) * 64 + cs]);
#pragma unroll
            for (int ni = 0; ni < 2; ni++)
                bf2[ni] = *reinterpret_cast<const short8*>(
                    &Bs[cur][(wc * 32 + ni * 16 + lrow) * 64 + cs]);
#pragma unroll
            for (int mi = 0; mi < 2; mi++)
#pragma unroll
                for (int ni = 0; ni < 2; ni++)
                    acc[mi][ni] = __builtin_amdgcn_mfma_f32_16x16x32_bf16(af[mi], bf2[ni], acc[mi][ni], 0, 0, 0);
        }
        if constexpr (F32B) {
            if (kt + 1 < NT) writeB(cur ^ 1, u0, u1);   // cvt+write after compute
        }
        __syncthreads();   // WAR + vmcnt/lgkmcnt drain (next tile resident after this)
    }
#pragma unroll
    for (int mi = 0; mi < 2; mi++)
#pragma unroll
        for (int ni = 0; ni < 2; ni++)
#pragma unroll
            for (int r = 0; r < 4; r++) {
                int row = m0 + wr * 32 + mi * 16 + lk * 4 + r;
                int col = n0 + wc * 32 + ni * 16 + lrow;
                if constexpr (OUTMODE == 0)
                    Cb[(size_t)row * N + col] = f2bf(acc[mi][ni][r]);
                else
                    Cf[(size_t)row * N + col] = acc[mi][ni][r] + bias[col];
            }
}

// ---------------- causal Toeplitz conv, shared B-tile, half-group blocks (R12) ---------------
__global__ __launch_bounds__(256) void conv2(const u16* __restrict__ zr,
                                             const u16* __restrict__ vt2,
                                             u16* __restrict__ cv) {
    const int i = blockIdx.x;
    const int bh = (i & 7) * 4 + ((i >> 3) & 3);   // 4 bh per XCD
    const int rest = i >> 5;                        // 0..31
    const int ch = rest & 1;
    const int gm = (rest >> 1) & 7;                 // group 0..7 (256 rows each)
    const int half = rest >> 4;                     // 0..1 (128-row half)
    const int b = bh >> 4, h = bh & 15;
    __shared__ uint zsl[2176];       // dual-parity zrev (8.5 KB)
    __shared__ u16 Bt[2][32 * 64];   // B tile dbuf (8 KB)
    const int t = threadIdx.x;
    {
        const uint* zp = reinterpret_cast<const uint*>(zr + (size_t)bh * ZP);
        for (int q = t; q < 1088; q += 256) {
            uint v0 = (q < 1056) ? zp[q] : 0u;
            uint v1 = (q < 1055) ? zp[q + 1] : 0u;
            zsl[q] = v0;
            zsl[1088 + q] = (v0 >> 16) | (v1 << 16);
        }
    }
    const int w = t >> 6, l = t & 63;
    const int lrow = l & 15, lk = l >> 4, lk8 = lk * 8;
    const int ebase = h * 64 + ch * 32;
    const size_t boff = (size_t)b * SEQ;

    const int rB = w * 8 + (l >> 3);
    const int Csrc = (l & 7) ^ (rB & 7);
    const u16* gB = vt2 + (((size_t)(ebase + rB)) << 12) + boff + Csrc * 8;
    const int dbase = w * 512;                      // u16 units
    __syncthreads();                                // zsl ready

    union U { uint d[4]; short8 s8; };
    const int r0 = gm * 256 + half * 128 + w * 32;  // this wave's 32 rows
    const int wkmax = r0 + 32;
    const int ns = gm * 4 + half * 2 + 2;           // K64 steps (covers max row+1)
    const int obase0 = 2047 - r0 - lrow + lk8;
    f32x4 acc[2][2];
#pragma unroll
    for (int a = 0; a < 2; a++)
#pragma unroll
        for (int c = 0; c < 2; c++) acc[a][c] = (f32x4){0.f, 0.f, 0.f, 0.f};

    gload16(gB, &Bt[0][dbase]);                     // prologue stage k0=0
    for (int s = 0; s < ns; s++) {
        const int cur = s & 1;
        const int k0 = s * 64;
        if (s + 1 < ns) gload16(gB + k0 + 64, &Bt[cur ^ 1][dbase]);
        __syncthreads();                            // tile s resident
        if (k0 < wkmax) {
#pragma unroll
            for (int kk = 0; kk < 2; kk++) {
                U af[2];
                short8 bf2[2];
#pragma unroll
                for (int mi = 0; mi < 2; mi++) {
                    int o = obase0 - mi * 16 + k0 + kk * 32;
                    uint adw = (uint)(o >> 1) + (uint)((o & 1) * 1088);
#pragma unroll
                    for (int q = 0; q < 4; q++) af[mi].d[q] = zsl[adw + q];
                }
#pragma unroll
                for (int ni = 0; ni < 2; ni++) {
                    int row = ni * 16 + lrow;
                    int c2 = (((kk * 4 + lk) ^ (row & 7))) * 8;
                    bf2[ni] = *reinterpret_cast<const short8*>(&Bt[cur][row * 64 + c2]);
                }
#pragma unroll
                for (int mi = 0; mi < 2; mi++)
#pragma unroll
                    for (int ni = 0; ni < 2; ni++)
                        acc[mi][ni] = __builtin_amdgcn_mfma_f32_16x16x32_bf16(af[mi].s8, bf2[ni], acc[mi][ni], 0, 0, 0);
            }
        }
        __syncthreads();                            // reads done before overwrite
    }
#pragma unroll
    for (int mi = 0; mi < 2; mi++)
#pragma unroll
        for (int ni = 0; ni < 2; ni++)
#pragma unroll
            for (int rr = 0; rr < 4; rr++) {
                int row = r0 + mi * 16 + lk * 4 + rr;
                int col = ebase + ni * 16 + lrow;
                cv[((size_t)b * SEQ + row) * EMB + col] = f2bf(acc[mi][ni][rr]);
            }
}

extern "C" void kernel_launch(void* const* d_in, const int* in_sizes, int n_in,
                              void* d_out, int out_size, void* d_ws, size_t ws_size,
                              hipStream_t stream) {
    const float* x   = (const float*)d_in[0];
    const float* W_A = (const float*)d_in[1];
    const float* W_V = (const float*)d_in[2];
    const float* W_O = (const float*)d_in[3];
    const float* b_O = (const float*)d_in[4];

    char* ws = (char*)d_ws;
    u16*   wvb = (u16*)(ws + 8388608);    // 2 MB   W_V bf16 [1024][1024]
    u16*   wob = (u16*)(ws + 10485760);   // 2 MB   W_O bf16
    float* zl  = (float*)(ws + 12582912); // 256 KB logits fp32 [B][H][S]
    u16*   zr  = (u16*)(ws + 12845056);   // 132 KB reversed softmax bf16 [B][H][ZP]
    u16*   vt2 = (u16*)(ws + 12980224);   // 8 MB   v^T bf16 [1024][B*S]
    u16*   cv  = (u16*)(ws + 21368832);   // 8 MB   conv out bf16 [4096][1024]

    cast_w<<<2048, 256, 0, stream>>>(W_V, W_O, wvb, wob);
    logits_kernel<<<256, 256, 0, stream>>>(x, W_A, zl);
    // v^T[e][b*S+s] = sum_k W_V[e,k] * x[b,s,k]; B read fp32 from x directly.
    // blocks 512..543 do softmax
    gemm32<0, 0, true, true><<<544, 512, 0, stream>>>(wvb, nullptr, x, vt2, nullptr, nullptr,
                                                      1024, 4096, 1024, zl, zr);
    conv2<<<1024, 256, 0, stream>>>(zr, vt2, cv);
    gemm32<1, 1, false, false><<<512, 512, 0, stream>>>(cv, wob, nullptr, nullptr, (float*)d_out, b_O,
                                                        4096, 1024, 1024, nullptr, nullptr);
}

// Round 17
// 89.230 us; speedup vs baseline: 1.0282x; 1.0282x over previous
//
#include <hip/hip_runtime.h>
#include <hip/hip_bf16.h>
#include <stdint.h>

typedef unsigned short u16;
typedef short short8 __attribute__((ext_vector_type(8)));
typedef float f32x4 __attribute__((ext_vector_type(4)));

#define SEQ 2048
#define EMB 1024
#define NH 16
#define HD 64
#define ZP 2112  // SEQ + 64 pad, reversed z per (b,h)

__device__ inline u16 f2bf(float f) {
    uint32_t u = __builtin_bit_cast(uint32_t, f);
    uint32_t r = (u + 0x7FFFu + ((u >> 16) & 1u)) >> 16;
    return (u16)r;
}

__device__ inline void gload16(const void* g, void* l) {
    __builtin_amdgcn_global_load_lds(
        (const __attribute__((address_space(1))) void*)g,
        (__attribute__((address_space(3))) void*)l, 16, 0, 0);
}

// ---------------- fused: x cast->bf16 + logits; W_V/W_O cast in tail blocks ----------------
__global__ __launch_bounds__(256) void cast_logits(const float* __restrict__ x,
                                                   const float* __restrict__ W_A,
                                                   const float* __restrict__ W_V,
                                                   const float* __restrict__ W_O,
                                                   u16* __restrict__ xb,
                                                   u16* __restrict__ wvb,
                                                   u16* __restrict__ wob,
                                                   float* __restrict__ zl) {
    const int bid = blockIdx.x, t = threadIdx.x;
    if (bid >= 256) {
        int j = (bid - 256) * 256 + t;
        const float* src;
        u16* dst;
        if (j < 262144) { src = W_V; dst = wvb; }
        else { j -= 262144; src = W_O; dst = wob; }
        float4 f = reinterpret_cast<const float4*>(src)[j];
        union { u16 u[4]; uint2 v; } o;
        o.u[0] = f2bf(f.x); o.u[1] = f2bf(f.y); o.u[2] = f2bf(f.z); o.u[3] = f2bf(f.w);
        reinterpret_cast<uint2*>(dst)[j] = o.v;
        return;
    }
    __shared__ float wa[NH * EMB]; // 64 KB
    for (int i = t; i < NH * EMB / 4; i += 256)
        reinterpret_cast<float4*>(wa)[i] = reinterpret_cast<const float4*>(W_A)[i];
    __syncthreads();
    const int w = t >> 6, l = t & 63;
    const int row0 = bid * 16 + w * 4;
    for (int rr = 0; rr < 4; rr++) {
        int gs = row0 + rr;           // 0..4095 = b*SEQ + s
        int b = gs >> 11, s = gs & 2047;
        const float* xr = x + (size_t)gs * EMB;
        float xv[16];
#pragma unroll
        for (int q = 0; q < 16; q++) xv[q] = xr[l + 64 * q];
        u16* xw = xb + (size_t)gs * EMB;
#pragma unroll
        for (int q = 0; q < 16; q++) xw[l + 64 * q] = f2bf(xv[q]);
#pragma unroll
        for (int h = 0; h < NH; h++) {
            float a = 0.f;
#pragma unroll
            for (int q = 0; q < 16; q++) a += xv[q] * wa[h * EMB + l + 64 * q];
#pragma unroll
            for (int off = 32; off; off >>= 1) a += __shfl_xor(a, off);
            if (l == h) zl[((size_t)b * NH + h) * SEQ + s] = a * 0.125f;
        }
    }
}

// ---------------- softmax body (per bh), 512 threads ----------------
__device__ void softmax_body512(const float* __restrict__ zl, u16* __restrict__ zr, int bh) {
    const float* src = zl + (size_t)bh * SEQ;
    int t = threadIdx.x;
    int w = t >> 6, l = t & 63;
    __shared__ float red[8];
    __shared__ float bc;
    float v[4];
#pragma unroll
    for (int q = 0; q < 4; q++) v[q] = src[t + 512 * q];
    float m = fmaxf(fmaxf(v[0], v[1]), fmaxf(v[2], v[3]));
#pragma unroll
    for (int off = 32; off; off >>= 1) m = fmaxf(m, __shfl_xor(m, off));
    if (l == 0) red[w] = m;
    __syncthreads();
    if (t == 0) {
        float mm = red[0];
#pragma unroll
        for (int q = 1; q < 8; q++) mm = fmaxf(mm, red[q]);
        bc = mm;
    }
    __syncthreads();
    m = bc;
    float s = 0.f;
#pragma unroll
    for (int q = 0; q < 4; q++) { v[q] = expf(v[q] - m); s += v[q]; }
#pragma unroll
    for (int off = 32; off; off >>= 1) s += __shfl_xor(s, off);
    if (l == 0) red[w] = s;
    __syncthreads();
    if (t == 0) {
        float ss = 0.f;
#pragma unroll
        for (int q = 0; q < 8; q++) ss += red[q];
        bc = ss;
    }
    __syncthreads();
    float inv = 1.0f / bc;
#pragma unroll
    for (int q = 0; q < 4; q++) {
        int sidx = t + 512 * q;
        zr[(size_t)bh * ZP + (SEQ - 1 - sidx)] = f2bf(v[q] * inv);
    }
    if (t < ZP - SEQ) zr[(size_t)bh * ZP + SEQ + t] = 0;
}

// ---------------- GEMM: C[M,N] = A[M,K] * B[N,K]^T -- R12 geometry @ 24 waves/CU -------------
// 128x64 tile, 512 threads = 8 waves (4 row-groups x 2 col-groups), wave 32x32
// acc[2][2], BK=64 dbuf, plain __syncthreads 2-phase (89.5us-best loop).
// ONLY change: __launch_bounds__(512, 6) -> 3 blocks/CU (LDS 48KB x 3 = 144 <= 160),
// 24 waves/CU. Cross-block TLP is the only lever that has repeatedly paid
// (R11: 8->16 waves = -3.6us; R12 conv 4->16 = -6.9us); this is the last rung.
// Swizzle pair (rule #21): source c=(l&7)^(l>>3), read ck^(lrow&7) -> 2-way, free.
// OUTMODE 0: bf16 out; 1: fp32 out + bias. SM: tail softmax.
template <int OUTMODE, int MAP, bool SM>
__global__ __launch_bounds__(512, 6) void gemm32(const u16* __restrict__ A,
                                                 const u16* __restrict__ Bw,
                                                 u16* __restrict__ Cb, float* __restrict__ Cf,
                                                 const float* __restrict__ bias,
                                                 int M, int N, int K,
                                                 const float* __restrict__ zl,
                                                 u16* __restrict__ zr) {
    if constexpr (SM) {
        if (blockIdx.x >= 512) { softmax_body512(zl, zr, blockIdx.x - 512); return; }
    }
    __shared__ u16 As[2][128 * 64];   // 16 KB each
    __shared__ u16 Bs[2][64 * 64];    //  8 KB each -> 48 KB total
    const int t = threadIdx.x;
    const int i = blockIdx.x;
    int xg, yg;
    if constexpr (MAP == 0) { xg = (i & 7) * 8 + ((i >> 3) & 7); yg = i >> 6; }
    else                    { yg = (i & 7) * 4 + ((i >> 3) & 3); xg = i >> 5; }
    const int m0 = yg * 128, n0 = xg * 64;
    const int w = t >> 6, l = t & 63;
    const int wr = w & 3, wc = w >> 2;        // wave tile 32 rows x 32 cols
    const int lrow = l & 15, lk = l >> 4;
    const int r7 = lrow & 7;

    const int csrc = ((l & 7) ^ (l >> 3)) * 8;     // u16 offset within BK row
    const u16* gA0 = A + (size_t)(m0 + w * 16 + (l >> 3)) * K + csrc;
    const u16* gA1 = gA0 + (size_t)8 * K;
    const u16* gB = Bw + (size_t)(n0 + w * 8 + (l >> 3)) * K + csrc;
    const int dA0 = w * 1024, dA1 = w * 1024 + 512, dB = w * 512;  // u16 units

    f32x4 acc[2][2];
#pragma unroll
    for (int a = 0; a < 2; a++)
#pragma unroll
        for (int b = 0; b < 2; b++) acc[a][b] = (f32x4){0.f, 0.f, 0.f, 0.f};

    const int NT = K >> 6;
    gload16(gA0, &As[0][dA0]);
    gload16(gA1, &As[0][dA1]);
    gload16(gB, &Bs[0][dB]);
    __syncthreads();

    for (int kt = 0; kt < NT; kt++) {
        const int cur = kt & 1;
        if (kt + 1 < NT) {
            const int k0 = (kt + 1) * 64;
            gload16(gA0 + k0, &As[cur ^ 1][dA0]);
            gload16(gA1 + k0, &As[cur ^ 1][dA1]);
            gload16(gB + k0, &Bs[cur ^ 1][dB]);
        }
#pragma unroll
        for (int kk = 0; kk < 2; kk++) {
            const int cs = ((kk * 4 + lk) ^ r7) * 8;
            short8 af[2], bf2[2];
#pragma unroll
            for (int mi = 0; mi < 2; mi++)
                af[mi] = *reinterpret_cast<const short8*>(
                    &As[cur][(wr * 32 + mi * 16 + lrow) * 64 + cs]);
#pragma unroll
            for (int ni = 0; ni < 2; ni++)
                bf2[ni] = *reinterpret_cast<const short8*>(
                    &Bs[cur][(wc * 32 + ni * 16 + lrow) * 64 + cs]);
#pragma unroll
            for (int mi = 0; mi < 2; mi++)
#pragma unroll
                for (int ni = 0; ni < 2; ni++)
                    acc[mi][ni] = __builtin_amdgcn_mfma_f32_16x16x32_bf16(af[mi], bf2[ni], acc[mi][ni], 0, 0, 0);
        }
        __syncthreads();   // WAR + vmcnt drain (next tile resident after this)
    }
#pragma unroll
    for (int mi = 0; mi < 2; mi++)
#pragma unroll
        for (int ni = 0; ni < 2; ni++)
#pragma unroll
            for (int r = 0; r < 4; r++) {
                int row = m0 + wr * 32 + mi * 16 + lk * 4 + r;
                int col = n0 + wc * 32 + ni * 16 + lrow;
                if constexpr (OUTMODE == 0)
                    Cb[(size_t)row * N + col] = f2bf(acc[mi][ni][r]);
                else
                    Cf[(size_t)row * N + col] = acc[mi][ni][r] + bias[col];
            }
}

// ---------------- causal Toeplitz conv, shared B-tile, half-group blocks (R12) ---------------
__global__ __launch_bounds__(256) void conv2(const u16* __restrict__ zr,
                                             const u16* __restrict__ vt2,
                                             u16* __restrict__ cv) {
    const int i = blockIdx.x;
    const int bh = (i & 7) * 4 + ((i >> 3) & 3);   // 4 bh per XCD
    const int rest = i >> 5;                        // 0..31
    const int ch = rest & 1;
    const int gm = (rest >> 1) & 7;                 // group 0..7 (256 rows each)
    const int half = rest >> 4;                     // 0..1 (128-row half)
    const int b = bh >> 4, h = bh & 15;
    __shared__ uint zsl[2176];       // dual-parity zrev (8.5 KB)
    __shared__ u16 Bt[2][32 * 64];   // B tile dbuf (8 KB)
    const int t = threadIdx.x;
    {
        const uint* zp = reinterpret_cast<const uint*>(zr + (size_t)bh * ZP);
        for (int q = t; q < 1088; q += 256) {
            uint v0 = (q < 1056) ? zp[q] : 0u;
            uint v1 = (q < 1055) ? zp[q + 1] : 0u;
            zsl[q] = v0;
            zsl[1088 + q] = (v0 >> 16) | (v1 << 16);
        }
    }
    const int w = t >> 6, l = t & 63;
    const int lrow = l & 15, lk = l >> 4, lk8 = lk * 8;
    const int ebase = h * 64 + ch * 32;
    const size_t boff = (size_t)b * SEQ;

    const int rB = w * 8 + (l >> 3);
    const int Csrc = (l & 7) ^ (rB & 7);
    const u16* gB = vt2 + (((size_t)(ebase + rB)) << 12) + boff + Csrc * 8;
    const int dbase = w * 512;                      // u16 units
    __syncthreads();                                // zsl ready

    union U { uint d[4]; short8 s8; };
    const int r0 = gm * 256 + half * 128 + w * 32;  // this wave's 32 rows
    const int wkmax = r0 + 32;
    const int ns = gm * 4 + half * 2 + 2;           // K64 steps (covers max row+1)
    const int obase0 = 2047 - r0 - lrow + lk8;
    f32x4 acc[2][2];
#pragma unroll
    for (int a = 0; a < 2; a++)
#pragma unroll
        for (int c = 0; c < 2; c++) acc[a][c] = (f32x4){0.f, 0.f, 0.f, 0.f};

    gload16(gB, &Bt[0][dbase]);                     // prologue stage k0=0
    for (int s = 0; s < ns; s++) {
        const int cur = s & 1;
        const int k0 = s * 64;
        if (s + 1 < ns) gload16(gB + k0 + 64, &Bt[cur ^ 1][dbase]);
        __syncthreads();                            // tile s resident
        if (k0 < wkmax) {
#pragma unroll
            for (int kk = 0; kk < 2; kk++) {
                U af[2];
                short8 bf2[2];
#pragma unroll
                for (int mi = 0; mi < 2; mi++) {
                    int o = obase0 - mi * 16 + k0 + kk * 32;
                    uint adw = (uint)(o >> 1) + (uint)((o & 1) * 1088);
#pragma unroll
                    for (int q = 0; q < 4; q++) af[mi].d[q] = zsl[adw + q];
                }
#pragma unroll
                for (int ni = 0; ni < 2; ni++) {
                    int row = ni * 16 + lrow;
                    int c2 = (((kk * 4 + lk) ^ (row & 7))) * 8;
                    bf2[ni] = *reinterpret_cast<const short8*>(&Bt[cur][row * 64 + c2]);
                }
#pragma unroll
                for (int mi = 0; mi < 2; mi++)
#pragma unroll
                    for (int ni = 0; ni < 2; ni++)
                        acc[mi][ni] = __builtin_amdgcn_mfma_f32_16x16x32_bf16(af[mi].s8, bf2[ni], acc[mi][ni], 0, 0, 0);
            }
        }
        __syncthreads();                            // reads done before overwrite
    }
#pragma unroll
    for (int mi = 0; mi < 2; mi++)
#pragma unroll
        for (int ni = 0; ni < 2; ni++)
#pragma unroll
            for (int rr = 0; rr < 4; rr++) {
                int row = r0 + mi * 16 + lk * 4 + rr;
                int col = ebase + ni * 16 + lrow;
                cv[((size_t)b * SEQ + row) * EMB + col] = f2bf(acc[mi][ni][rr]);
            }
}

extern "C" void kernel_launch(void* const* d_in, const int* in_sizes, int n_in,
                              void* d_out, int out_size, void* d_ws, size_t ws_size,
                              hipStream_t stream) {
    const float* x   = (const float*)d_in[0];
    const float* W_A = (const float*)d_in[1];
    const float* W_V = (const float*)d_in[2];
    const float* W_O = (const float*)d_in[3];
    const float* b_O = (const float*)d_in[4];

    char* ws = (char*)d_ws;
    u16*   xb  = (u16*)(ws + 0);          // 8 MB   x bf16 [4096][1024]
    u16*   wvb = (u16*)(ws + 8388608);    // 2 MB   W_V bf16 [1024][1024]
    u16*   wob = (u16*)(ws + 10485760);   // 2 MB   W_O bf16
    float* zl  = (float*)(ws + 12582912); // 256 KB logits fp32 [B][H][S]
    u16*   zr  = (u16*)(ws + 12845056);   // 132 KB reversed softmax bf16 [B][H][ZP]
    u16*   vt2 = (u16*)(ws + 12980224);   // 8 MB   v^T bf16 [1024][B*S]
    u16*   cv  = (u16*)(ws + 21368832);   // 8 MB   conv out bf16 [4096][1024]

    cast_logits<<<2304, 256, 0, stream>>>(x, W_A, W_V, W_O, xb, wvb, wob, zl);
    // v^T[e][b*S+s] = sum_k W_V[e,k] * x[b,s,k]; blocks 512..543 do softmax
    gemm32<0, 0, true><<<544, 512, 0, stream>>>(wvb, xb, vt2, nullptr, nullptr,
                                                1024, 4096, 1024, zl, zr);
    conv2<<<1024, 256, 0, stream>>>(zr, vt2, cv);
    gemm32<1, 1, false><<<512, 512, 0, stream>>>(cv, wob, nullptr, (float*)d_out, b_O,
                                                 4096, 1024, 1024, nullptr, nullptr);
}